// Round 8
// baseline (138.710 us; speedup 1.0000x reference)
//
#include <hip/hip_runtime.h>

// SupConLoss, B=4096 D=256 L=20, T=0.07.
// lv_il = lp_i + m_i - masked_mean_il ; lp_i = log(expsum_i*e^{ci-m} + 1e-20)
// masked_sum via factorization: dot(F_i, Wt[5l+v]) - c_i, Wt = sum_j F_j onehot(lab_j), fp32.
// 3 dispatches: memset | fused{GEMM+row-atomics, counts, Wt} | final{per-row loss + scalar}.
// Cross-tile row reduce via atomics: es partials are ci-stabilized (sum is order-free),
// max via ordered-uint atomicMax.

#define B_N 4096
#define D_K 256
#define L_N 20
#define INVT 14.285714285714286f

// ws layout (bytes). One memset covers [WT_OFF, EP_OFF+16K) = 0x10000..0x32000.
#define CNT_OFF  0x004000u  // int [20][5] (written by counts blocks)
#define WT_OFF   0x010000u  // f32 [100][256] atomic-accumulated (memset 0)
#define ACC_OFF  0x029000u  // f32 Ls[20], Ss[20], u32 done-counter @+160 (memset 0)
#define MP_OFF   0x02A000u  // u32 [4096] ordered-float row max (memset 0 ~ -inf)
#define EP_OFF   0x02E000u  // f32 [4096] expsum (memset 0)

typedef __bf16 bf16x8 __attribute__((ext_vector_type(8)));
typedef float f32x4 __attribute__((ext_vector_type(4)));

struct __align__(16) U4 { unsigned int x, y, z, w; };

__device__ __forceinline__ U4 pack8(float4 a, float4 b) {
  bf16x8 v;
  v[0] = (__bf16)a.x; v[1] = (__bf16)a.y; v[2] = (__bf16)a.z; v[3] = (__bf16)a.w;
  v[4] = (__bf16)b.x; v[5] = (__bf16)b.y; v[6] = (__bf16)b.z; v[7] = (__bf16)b.w;
  return __builtin_bit_cast(U4, v);  // compiler emits v_cvt_pk_bf16_f32 pairs
}

__device__ __forceinline__ unsigned int ordf(float x) {  // monotone float->uint
  unsigned int u = __float_as_uint(x);
  return (u & 0x80000000u) ? ~u : (u | 0x80000000u);
}
__device__ __forceinline__ float ordinv(unsigned int o) {
  return __uint_as_float((o & 0x80000000u) ? (o & 0x7FFFFFFFu) : ~o);
}

// ---------------- fused: F@F^T row-reduce GEMM (0..255) | counts (256..275) | Wt (276..435) --------
__global__ __launch_bounds__(512, 2) void k_fused(const float* __restrict__ F,
                                                  const int* __restrict__ lab,
                                                  unsigned char* __restrict__ ws) {
  __shared__ unsigned char smem[67584];  // 64K B-panel | 2K scvec
  const int bid = blockIdx.x, t = threadIdx.x;
  if (bid < 256) {
    const int w = t >> 6, l = t & 63;
    const int lr = l & 15, lg = l >> 4;
    // 2-D XCD partition (perf-only)
    const int r = bid & 7, s = bid >> 3;
    const int bm = ((r & 3) << 1) | (s & 1);
    const int bn = ((r >> 2) << 4) | (s >> 1);
    const int rowbase = bm * 512 + w * 64;
    const int colb = bn * 128;
    // stage B-panel rows [colb..colb+128): fp32 -> bf16 -> swizzled LDS
    {
      const int srow = t >> 2, q = t & 3;
      const float* src = F + (colb + srow) * 256 + q * 64;
      #pragma unroll
      for (int i = 0; i < 8; ++i) {
        float4 f0 = *(const float4*)(src + i * 8);
        float4 f1 = *(const float4*)(src + i * 8 + 4);
        const int kb = q * 128 + i * 16;
        *(U4*)(smem + srow * 512 + (kb ^ ((srow & 7) << 4))) = pack8(f0, f1);
      }
    }
    __syncthreads();
    unsigned int* MP = (unsigned int*)(ws + MP_OFF);
    float* EP = (float*)(ws + EP_OFF);
    float* scv = (float*)(smem + 65536);       // [8 waves][64 rows] c_i for own rows
    const float* arow0 = F + (rowbase + lr) * 256 + lg * 8;
    float ssq[4] = {0.f, 0.f, 0.f, 0.f};
    #pragma unroll 1
    for (int tile = 0; tile < 2; ++tile) {
      f32x4 acc[4][4] = {};
      #pragma unroll 1
      for (int kk = 0; kk < 8; ++kk) {
        bf16x8 afr[4];
        #pragma unroll
        for (int mi = 0; mi < 4; ++mi) {
          const float* ap = arow0 + mi * 16 * 256 + kk * 32;
          float4 a0 = *(const float4*)(ap);
          float4 a1 = *(const float4*)(ap + 4);
          if (tile == 0)
            ssq[mi] += a0.x * a0.x + a0.y * a0.y + a0.z * a0.z + a0.w * a0.w
                     + a1.x * a1.x + a1.y * a1.y + a1.z * a1.z + a1.w * a1.w;
          afr[mi] = __builtin_bit_cast(bf16x8, pack8(a0, a1));
        }
        bf16x8 bfr[4];
        #pragma unroll
        for (int n = 0; n < 4; ++n) {
          const int brow = tile * 64 + n * 16 + lr;
          const int kb = kk * 64 + lg * 16;
          bfr[n] = __builtin_bit_cast(bf16x8,
              *(const U4*)(smem + brow * 512 + (kb ^ ((brow & 7) << 4))));
        }
        #pragma unroll
        for (int mi = 0; mi < 4; ++mi)
          #pragma unroll
          for (int n = 0; n < 4; ++n)
            acc[mi][n] = __builtin_amdgcn_mfma_f32_16x16x32_bf16(afr[mi], bfr[n], acc[mi][n], 0, 0, 0);
      }
      if (tile == 0) {
        // finish per-row sumsq: lanes {lr, lr+16, lr+32, lr+48} hold partials of row mi*16+lr
        #pragma unroll
        for (int mi = 0; mi < 4; ++mi) {
          float ss = ssq[mi];
          ss += __shfl_xor(ss, 16, 64);
          ss += __shfl_xor(ss, 32, 64);
          if (lg == 0) scv[w * 64 + mi * 16 + lr] = ss * INVT;
        }
      }
      #pragma unroll
      for (int mi = 0; mi < 4; ++mi) {
        #pragma unroll
        for (int rr = 0; rr < 4; ++rr) {
          const int row = rowbase + mi * 16 + lg * 4 + rr;
          const float crow = scv[w * 64 + mi * 16 + lg * 4 + rr];
          float vm = -3.4e38f, es = 0.f;
          #pragma unroll
          for (int n = 0; n < 4; ++n) {
            const int col = colb + tile * 64 + n * 16 + lr;
            const float v = acc[mi][n][rr] * INVT;
            vm = fmaxf(vm, v);
            const float e = __expf(v - crow);
            es += (col == row) ? 0.f : e;  // exclude diagonal from expsum
          }
          #pragma unroll
          for (int off = 1; off < 16; off <<= 1) {
            vm = fmaxf(vm, __shfl_xor(vm, off, 16));
            es += __shfl_xor(es, off, 16);
          }
          if (lr == 0) {
            atomicMax(MP + row, ordf(vm));
            atomicAdd(EP + row, es);
          }
        }
      }
    }
  } else if (bid < 276) {
    // counts[l][v], 512 threads
    __shared__ int sc[8][5];
    const int l = bid - 256;
    int c0 = 0, c1 = 0, c2 = 0, c3 = 0, c4 = 0;
    for (int j = t; j < B_N; j += 512) {
      int v = lab[j * L_N + l];
      c0 += (v == 0); c1 += (v == 1); c2 += (v == 2); c3 += (v == 3); c4 += (v == 4);
    }
    #pragma unroll
    for (int off = 1; off < 64; off <<= 1) {
      c0 += __shfl_xor(c0, off, 64); c1 += __shfl_xor(c1, off, 64);
      c2 += __shfl_xor(c2, off, 64); c3 += __shfl_xor(c3, off, 64);
      c4 += __shfl_xor(c4, off, 64);
    }
    const int w = t >> 6;
    if ((t & 63) == 0) { sc[w][0] = c0; sc[w][1] = c1; sc[w][2] = c2; sc[w][3] = c3; sc[w][4] = c4; }
    __syncthreads();
    if (t < 5) {
      int s5 = 0;
      #pragma unroll
      for (int ww = 0; ww < 8; ++ww) s5 += sc[ww][t];
      ((int*)(ws + CNT_OFF))[l * 5 + t] = s5;
    }
  } else {
    // Wt[5l+v][d] += F[j][d] over a 512-j block (two 256-halves), reg accumulate + 5 atomics
    int* slab = (int*)smem;
    const int idx = bid - 276;           // 0..159
    const int l = idx >> 3, jblk = idx & 7;
    const int j0 = jblk * 512;
    slab[t] = lab[(j0 + t) * L_N + l];
    __syncthreads();
    const int d = t & 255, half = t >> 8;
    const int base = half * 256;
    float a0 = 0, a1 = 0, a2 = 0, a3 = 0, a4 = 0;
    #pragma unroll 16
    for (int jj = 0; jj < 256; ++jj) {
      const int v = slab[base + jj];
      const float x = F[(j0 + base + jj) * 256 + d];
      a0 += (v == 0) ? x : 0.f;
      a1 += (v == 1) ? x : 0.f;
      a2 += (v == 2) ? x : 0.f;
      a3 += (v == 3) ? x : 0.f;
      a4 += (v == 4) ? x : 0.f;
    }
    float* Wt = (float*)(ws + WT_OFF);
    atomicAdd(Wt + (l * 5 + 0) * 256 + d, a0);
    atomicAdd(Wt + (l * 5 + 1) * 256 + d, a1);
    atomicAdd(Wt + (l * 5 + 2) * 256 + d, a2);
    atomicAdd(Wt + (l * 5 + 3) * 256 + d, a3);
    atomicAdd(Wt + (l * 5 + 4) * 256 + d, a4);
  }
}

// ---------------- final: per-row loss (wave-per-row, Wt direct from L2) + last-block scalar -------
__global__ __launch_bounds__(1024) void k_final(const float* __restrict__ F,
                                                const int* __restrict__ lab,
                                                unsigned char* __restrict__ ws,
                                                float* __restrict__ out) {
  __shared__ float sL[16][20], sS[16][20];
  const int t = threadIdx.x, w = t >> 6, l = t & 63;
  const int i = blockIdx.x * 16 + w;
  const float4 Ff = *(const float4*)(F + i * 256 + l * 4);
  float ci = Ff.x * Ff.x + Ff.y * Ff.y + Ff.z * Ff.z + Ff.w * Ff.w;
  #pragma unroll
  for (int off = 1; off < 64; off <<= 1) ci += __shfl_xor(ci, off, 64);
  ci *= INVT;
  const float m = ordinv(((const unsigned int*)(ws + MP_OFF))[i]);
  const float e = ((const float*)(ws + EP_OFF))[i];
  const float lp = logf(e * __expf(ci - m) + 1e-20f);
  const float* Wt = (const float*)(ws + WT_OFF);
  const int* cnts = (const int*)(ws + CNT_OFF);
  for (int ll = 0; ll < 20; ++ll) {
    const int v = lab[i * 20 + ll];
    const int cnt = cnts[ll * 5 + v] - 1;  // exclude self
    float lv = 0.f, sg = 0.f;
    if (cnt > 0) {
      const float4 Wf = *(const float4*)(Wt + (ll * 5 + v) * 256 + l * 4);  // coalesced, L2-hot
      float p = Ff.x * Wf.x + Ff.y * Wf.y + Ff.z * Wf.z + Ff.w * Wf.w;
      #pragma unroll
      for (int off = 1; off < 64; off <<= 1) p += __shfl_xor(p, off, 64);
      const float me = p * INVT - ci;  // masked sum excl self, S units
      lv = lp - (me - (float)cnt * m) / (float)cnt;
    } else {
      sg = 1.f;
    }
    if (l == 0) { sL[w][ll] = lv; sS[w][ll] = sg; }
  }
  __syncthreads();
  float* ACC = (float*)(ws + ACC_OFF);
  if (t < 20) {
    float Lsum = 0.f, Ssum = 0.f;
    #pragma unroll
    for (int ww = 0; ww < 16; ++ww) { Lsum += sL[ww][t]; Ssum += sS[ww][t]; }
    atomicAdd(ACC + t, Lsum);
    atomicAdd(ACC + 20 + t, Ssum);
  }
  __syncthreads();
  if (t == 0) {
    __threadfence();
    unsigned int done = atomicAdd((unsigned int*)(ws + ACC_OFF + 160), 1u);
    if (done == 255) {  // last block: final scalar
      float v = 0.f;
      #pragma unroll
      for (int ll = 0; ll < 20; ++ll) {
        float Ls = __hip_atomic_load(ACC + ll, __ATOMIC_RELAXED, __HIP_MEMORY_SCOPE_AGENT);
        float Ss = __hip_atomic_load(ACC + 20 + ll, __ATOMIC_RELAXED, __HIP_MEMORY_SCOPE_AGENT);
        v += Ls / (4096.f - Ss);
      }
      out[0] = v * 0.05f;
    }
  }
}

extern "C" void kernel_launch(void* const* d_in, const int* in_sizes, int n_in,
                              void* d_out, int out_size, void* d_ws, size_t ws_size,
                              hipStream_t stream) {
  const float* F = (const float*)d_in[0];
  const int* lab = (const int*)d_in[1];
  unsigned char* ws = (unsigned char*)d_ws;
  float* out = (float*)d_out;
  hipMemsetAsync(ws + WT_OFF, 0, 0x22000, stream);  // zero Wt + ACC + MP + EP
  k_fused<<<436, 512, 0, stream>>>(F, lab, ws);     // 256 GEMM + 20 counts + 160 Wt
  k_final<<<256, 1024, 0, stream>>>(F, lab, ws, out);
}